// Round 3
// baseline (664.354 us; speedup 1.0000x reference)
//
#include <hip/hip_runtime.h>

#define F 128
#define NN 65536
#define EE 16384
#define NNZT 786432

// ---------------- histogram (int4-vectorized: 4 nnz/thread) ----------------
__global__ void hist_kernel(const int4* __restrict__ hedge_idx4,
                            const int4* __restrict__ node_idx4,
                            int* __restrict__ cnt_e, int* __restrict__ cnt_n) {
    int i = blockIdx.x * 256 + threadIdx.x;
    int4 e = hedge_idx4[i];
    int4 n = node_idx4[i];
    atomicAdd(&cnt_e[e.x], 1);
    atomicAdd(&cnt_e[e.y], 1);
    atomicAdd(&cnt_e[e.z], 1);
    atomicAdd(&cnt_e[e.w], 1);
    atomicAdd(&cnt_n[n.x], 1);
    atomicAdd(&cnt_n[n.y], 1);
    atomicAdd(&cnt_n[n.z], 1);
    atomicAdd(&cnt_n[n.w], 1);
}

// ---------------- 3-phase exclusive scan (n multiple of 1024) ----------------
__global__ __launch_bounds__(1024) void scan_p1(const int* __restrict__ cnt,
                                                int* __restrict__ ofs,
                                                int* __restrict__ bsum) {
    __shared__ int wsum[16];
    int t = threadIdx.x, lane = t & 63, w = t >> 6;
    int g = blockIdx.x * 1024 + t;
    int v = cnt[g];
    int inc = v;
#pragma unroll
    for (int d = 1; d < 64; d <<= 1) {
        int u = __shfl_up(inc, d);
        if (lane >= d) inc += u;
    }
    if (lane == 63) wsum[w] = inc;
    __syncthreads();
    if (t < 16) {
        int s = wsum[t];
#pragma unroll
        for (int d = 1; d < 16; d <<= 1) {
            int u = __shfl_up(s, d);
            if (t >= d) s += u;
        }
        wsum[t] = s;  // inclusive scan of wave sums
    }
    __syncthreads();
    int woff = (w == 0) ? 0 : wsum[w - 1];
    ofs[g] = woff + inc - v;  // exclusive
    if (t == 1023) bsum[blockIdx.x] = wsum[15];
}

__global__ void scan_p2(int* __restrict__ bsum, int nb, int* __restrict__ ofs_end) {
    int lane = threadIdx.x;  // 64 threads
    int v = (lane < nb) ? bsum[lane] : 0;
    int inc = v;
#pragma unroll
    for (int d = 1; d < 64; d <<= 1) {
        int u = __shfl_up(inc, d);
        if (lane >= d) inc += u;
    }
    if (lane < nb) bsum[lane] = inc - v;  // exclusive block offsets
    if (lane == 63) *ofs_end = inc;       // grand total
}

__global__ __launch_bounds__(1024) void scan_p3(int* __restrict__ ofs,
                                                const int* __restrict__ bsum) {
    int g = blockIdx.x * 1024 + threadIdx.x;
    ofs[g] += bsum[blockIdx.x];
}

// ---------------- CSR fill (both directions, values pre-folded) ----------------
__global__ void fill_kernel(const int* __restrict__ node_idx, const int* __restrict__ hedge_idx,
                            const float* __restrict__ hd_vals, const float* __restrict__ hb_vals,
                            const float* __restrict__ dhwd_vals, const float* __restrict__ bhub_vals,
                            const int* __restrict__ ofs_e, const int* __restrict__ ofs_n,
                            int* __restrict__ cur_e, int* __restrict__ cur_n,
                            int* __restrict__ csr_e_node, float* __restrict__ csr_e_v1, float* __restrict__ csr_e_v2,
                            int* __restrict__ csr_n_edge, float* __restrict__ csr_n_v1, float* __restrict__ csr_n_v2) {
    int i = blockIdx.x * 256 + threadIdx.x;
    int e = hedge_idx[i];
    int n = node_idx[i];
    int pe = atomicAdd(&cur_e[e], 1);
    int oe = ofs_e[e] + pe;
    csr_e_node[oe] = n;
    csr_e_v1[oe] = 0.5f * hd_vals[i];   // ALPHA folded
    csr_e_v2[oe] = bhub_vals[i];
    int pn = atomicAdd(&cur_n[n], 1);
    int on = ofs_n[n] + pn;
    csr_n_edge[on] = e;
    csr_n_v1[on] = 0.5f * hb_vals[i];   // BETA folded
    csr_n_v2[on] = dhwd_vals[i];
}

// ---------------- fused dual GEMM: out1 = in@W1^T + b1 ; out2 = in@W2^T + b2 ----------------
__global__ __launch_bounds__(256) void gemm2_kernel(const float* __restrict__ in,
                                                    const float* __restrict__ W1, const float* __restrict__ b1,
                                                    float* __restrict__ out1,
                                                    const float* __restrict__ W2, const float* __restrict__ b2,
                                                    float* __restrict__ out2) {
    __shared__ float xs[64][132];
    int t = threadIdx.x;
    int row0 = blockIdx.x * 64;
    // stage 64x128 input tile
#pragma unroll
    for (int l = 0; l < 8; ++l) {
        int idx = t + l * 256;     // 0..2047 float4 slots
        int r = idx >> 5;
        int c4 = idx & 31;
        float4 v = *(const float4*)&in[(size_t)(row0 + r) * F + c4 * 4];
        *(float4*)&xs[r][c4 * 4] = v;
    }
    __syncthreads();
    int cbase = (t & 31) * 4;  // 4 consecutive output cols
    int rbase = (t >> 5) * 8;  // 8 consecutive rows
    float acc1[8][4] = {};
    float acc2[8][4] = {};
    for (int k0 = 0; k0 < F; k0 += 4) {
        float4 w1[4], w2[4];
#pragma unroll
        for (int j = 0; j < 4; ++j) {
            w1[j] = *(const float4*)&W1[(cbase + j) * F + k0];
            w2[j] = *(const float4*)&W2[(cbase + j) * F + k0];
        }
#pragma unroll
        for (int i = 0; i < 8; ++i) {
            float4 xv = *(const float4*)&xs[rbase + i][k0];
#pragma unroll
            for (int j = 0; j < 4; ++j) {
                acc1[i][j] += xv.x * w1[j].x + xv.y * w1[j].y + xv.z * w1[j].z + xv.w * w1[j].w;
                acc2[i][j] += xv.x * w2[j].x + xv.y * w2[j].y + xv.z * w2[j].z + xv.w * w2[j].w;
            }
        }
    }
    float4 bb1 = *(const float4*)&b1[cbase];
    float4 bb2 = *(const float4*)&b2[cbase];
#pragma unroll
    for (int i = 0; i < 8; ++i) {
        size_t r = (size_t)(row0 + rbase + i) * F + cbase;
        float4 o1, o2;
        o1.x = acc1[i][0] + bb1.x; o1.y = acc1[i][1] + bb1.y;
        o1.z = acc1[i][2] + bb1.z; o1.w = acc1[i][3] + bb1.w;
        o2.x = acc2[i][0] + bb2.x; o2.y = acc2[i][1] + bb2.y;
        o2.z = acc2[i][2] + bb2.z; o2.w = acc2[i][3] + bb2.w;
        *(float4*)&out1[r] = o1;
        *(float4*)&out2[r] = o2;
    }
}

// ---------------- gather-based segment-sum SpMM ----------------
// out[row] = init_scale*out[row] + sum_{j in row} val[j] * src[tgt[j]]
// One wave per row; lane covers float2 (row = 64 lanes * 8B = 512B).
// U-deep unroll => U independent row-gathers in flight per wave.
template <int U, bool NT>
__global__ __launch_bounds__(256) void spmm_gather(const int* __restrict__ ofs,
                                                   const int* __restrict__ tgt,
                                                   const float* __restrict__ val,
                                                   const float* __restrict__ src,
                                                   float* __restrict__ out,
                                                   float init_scale) {
    int row = blockIdx.x * 4 + (threadIdx.x >> 6);
    int lane = threadIdx.x & 63;
    int o0 = ofs[row], o1 = ofs[row + 1];
    int lo2 = lane * 2;
    float ax = 0.f, ay = 0.f;
    int j = o0;
    for (; j + U - 1 < o1; j += U) {
        int tg[U];
        float v[U];
#pragma unroll
        for (int u = 0; u < U; ++u) {
            tg[u] = tgt[j + u];
            v[u] = val[j + u];
        }
        float2 m[U];
#pragma unroll
        for (int u = 0; u < U; ++u) m[u] = *(const float2*)&src[(size_t)tg[u] * F + lo2];
#pragma unroll
        for (int u = 0; u < U; ++u) {
            ax += v[u] * m[u].x;
            ay += v[u] * m[u].y;
        }
    }
    for (; j < o1; ++j) {
        int tg = tgt[j];
        float v = val[j];
        float2 m = *(const float2*)&src[(size_t)tg * F + lo2];
        ax += v * m.x;
        ay += v * m.y;
    }
    float2* op = (float2*)&out[(size_t)row * F + lo2];
    if (init_scale != 0.0f) {
        float2 in0 = *op;
        ax += init_scale * in0.x;
        ay += init_scale * in0.y;
    }
    float2 o;
    o.x = ax;
    o.y = ay;
    if (NT) {
        double d;
        __builtin_memcpy(&d, &o, 8);
        __builtin_nontemporal_store(d, (double*)op);
    } else {
        *op = o;
    }
}

extern "C" void kernel_launch(void* const* d_in, const int* in_sizes, int n_in,
                              void* d_out, int out_size, void* d_ws, size_t ws_size,
                              hipStream_t stream) {
    const float* x = (const float*)d_in[0];
    const float* y = (const float*)d_in[1];
    const int* node_idx = (const int*)d_in[2];
    const int* hedge_idx = (const int*)d_in[3];
    const float* hd_vals = (const float*)d_in[4];
    const float* hb_vals = (const float*)d_in[5];
    const float* dhwd_vals = (const float*)d_in[6];
    const float* bhub_vals = (const float*)d_in[7];
    const float* Qv_w = (const float*)d_in[8];
    const float* Qv_b = (const float*)d_in[9];
    const float* Qe_w = (const float*)d_in[10];
    const float* Qe_b = (const float*)d_in[11];
    const float* Pe_w = (const float*)d_in[12];
    const float* Pe_b = (const float*)d_in[13];
    const float* Pv_w = (const float*)d_in[14];
    const float* Pv_b = (const float*)d_in[15];

    float* X = (float*)d_out;                   // final X [N,F]; scratch: qvx
    float* Y = (float*)d_out + (size_t)NN * F;  // final Y [E,F]; scratch: pey
    float* qvx = X;
    float* pey = Y;

    char* w = (char*)d_ws;
    float* t_n        = (float*)(w + 0);          // [N,F]  (holds pvx, then t_n)
    float* t_e        = (float*)(w + 33554432);   // [E,F]  (holds qey, then t_e)
    int*   csr_e_node = (int*)  (w + 41943040);
    float* csr_e_v1   = (float*)(w + 45088768);
    float* csr_e_v2   = (float*)(w + 48234496);
    int*   csr_n_edge = (int*)  (w + 51380224);
    float* csr_n_v1   = (float*)(w + 54525952);
    float* csr_n_v2   = (float*)(w + 57671680);
    int*   cnt_e      = (int*)  (w + 60817408);
    int*   cnt_n      = (int*)  (w + 60882944);
    int*   cur_e      = (int*)  (w + 61145088);
    int*   cur_n      = (int*)  (w + 61210624);
    int*   ofs_e      = (int*)  (w + 61472768);
    int*   ofs_n      = (int*)  (w + 61538560);
    int*   bsum       = (int*)  (w + 61800960);

    // zero cnt_e, cnt_n, cur_e, cur_n (contiguous 655360 B)
    hipMemsetAsync(cnt_e, 0, (size_t)2 * (EE + NN) * 4, stream);

    // histogram
    hist_kernel<<<NNZT / 1024, 256, 0, stream>>>((const int4*)hedge_idx, (const int4*)node_idx,
                                                 cnt_e, cnt_n);

    // scan edges (E = 16*1024)
    scan_p1<<<EE / 1024, 1024, 0, stream>>>(cnt_e, ofs_e, bsum);
    scan_p2<<<1, 64, 0, stream>>>(bsum, EE / 1024, &ofs_e[EE]);
    scan_p3<<<EE / 1024, 1024, 0, stream>>>(ofs_e, bsum);
    // scan nodes (N = 64*1024)
    scan_p1<<<NN / 1024, 1024, 0, stream>>>(cnt_n, ofs_n, bsum);
    scan_p2<<<1, 64, 0, stream>>>(bsum, NN / 1024, &ofs_n[NN]);
    scan_p3<<<NN / 1024, 1024, 0, stream>>>(ofs_n, bsum);

    // CSR fill
    fill_kernel<<<NNZT / 256, 256, 0, stream>>>(node_idx, hedge_idx, hd_vals, hb_vals,
                                                dhwd_vals, bhub_vals, ofs_e, ofs_n,
                                                cur_e, cur_n,
                                                csr_e_node, csr_e_v1, csr_e_v2,
                                                csr_n_edge, csr_n_v1, csr_n_v2);

    // GEMMs: qvx = x@Qv^T+b (into X region), t_n = pvx = x@Pv^T+b
    gemm2_kernel<<<NN / 64, 256, 0, stream>>>(x, Qv_w, Qv_b, qvx, Pv_w, Pv_b, t_n);
    // t_e = qey = y@Qe^T+b (ws), pey = y@Pe^T+b (into Y region)
    gemm2_kernel<<<EE / 64, 256, 0, stream>>>(y, Qe_w, Qe_b, t_e, Pe_w, Pe_b, pey);

    // phase A: t_e = 0.5*qey + seg_e(0.5*hd * qvx[node]) ; t_n = 0.5*pvx + seg_n(0.5*hb * pey[hedge])
    spmm_gather<8, false><<<EE / 4, 256, 0, stream>>>(ofs_e, csr_e_node, csr_e_v1, qvx, t_e, 0.5f);
    spmm_gather<4, false><<<NN / 4, 256, 0, stream>>>(ofs_n, csr_n_edge, csr_n_v1, pey, t_n, 0.5f);

    // phase B: X = seg_n(dhwd * t_e[hedge]) ; Y = seg_e(bhub * t_n[node])
    spmm_gather<4, true><<<NN / 4, 256, 0, stream>>>(ofs_n, csr_n_edge, csr_n_v2, t_e, X, 0.0f);
    spmm_gather<8, true><<<EE / 4, 256, 0, stream>>>(ofs_e, csr_e_node, csr_e_v2, t_n, Y, 0.0f);
}

// Round 7
// 555.913 us; speedup vs baseline: 1.1951x; 1.1951x over previous
//
#include <hip/hip_runtime.h>

#define F 128
#define NN 65536
#define EE 16384
#define NNZT 786432

typedef __attribute__((ext_vector_type(8))) short bfrag8;
typedef __attribute__((ext_vector_type(4))) float f32x4;

// round-to-nearest-even fp32 -> bf16 bits
__device__ __forceinline__ unsigned int bfrn(float f) {
    unsigned int u = __float_as_uint(f);
    return (u + 0x7fffu + ((u >> 16) & 1u)) >> 16;
}

// ---------------- histogram (int4-vectorized: 4 nnz/thread) ----------------
__global__ void hist_kernel(const int4* __restrict__ hedge_idx4,
                            const int4* __restrict__ node_idx4,
                            int* __restrict__ cnt_e, int* __restrict__ cnt_n) {
    int i = blockIdx.x * 256 + threadIdx.x;
    int4 e = hedge_idx4[i];
    int4 n = node_idx4[i];
    atomicAdd(&cnt_e[e.x], 1);
    atomicAdd(&cnt_e[e.y], 1);
    atomicAdd(&cnt_e[e.z], 1);
    atomicAdd(&cnt_e[e.w], 1);
    atomicAdd(&cnt_n[n.x], 1);
    atomicAdd(&cnt_n[n.y], 1);
    atomicAdd(&cnt_n[n.z], 1);
    atomicAdd(&cnt_n[n.w], 1);
}

// ---------------- 3-phase exclusive scan (n multiple of 1024) ----------------
__global__ __launch_bounds__(1024) void scan_p1(const int* __restrict__ cnt,
                                                int* __restrict__ ofs,
                                                int* __restrict__ bsum) {
    __shared__ int wsum[16];
    int t = threadIdx.x, lane = t & 63, w = t >> 6;
    int g = blockIdx.x * 1024 + t;
    int v = cnt[g];
    int inc = v;
#pragma unroll
    for (int d = 1; d < 64; d <<= 1) {
        int u = __shfl_up(inc, d);
        if (lane >= d) inc += u;
    }
    if (lane == 63) wsum[w] = inc;
    __syncthreads();
    if (t < 16) {
        int s = wsum[t];
#pragma unroll
        for (int d = 1; d < 16; d <<= 1) {
            int u = __shfl_up(s, d);
            if (t >= d) s += u;
        }
        wsum[t] = s;
    }
    __syncthreads();
    int woff = (w == 0) ? 0 : wsum[w - 1];
    ofs[g] = woff + inc - v;
    if (t == 1023) bsum[blockIdx.x] = wsum[15];
}

__global__ void scan_p2(int* __restrict__ bsum, int nb, int* __restrict__ ofs_end) {
    int lane = threadIdx.x;
    int v = (lane < nb) ? bsum[lane] : 0;
    int inc = v;
#pragma unroll
    for (int d = 1; d < 64; d <<= 1) {
        int u = __shfl_up(inc, d);
        if (lane >= d) inc += u;
    }
    if (lane < nb) bsum[lane] = inc - v;
    if (lane == 63) *ofs_end = inc;
}

__global__ __launch_bounds__(1024) void scan_p3(int* __restrict__ ofs,
                                                const int* __restrict__ bsum) {
    int g = blockIdx.x * 1024 + threadIdx.x;
    ofs[g] += bsum[blockIdx.x];
}

// ---------------- CSR fill ----------------
__global__ void fill_kernel(const int* __restrict__ node_idx, const int* __restrict__ hedge_idx,
                            const float* __restrict__ hd_vals, const float* __restrict__ hb_vals,
                            const float* __restrict__ dhwd_vals, const float* __restrict__ bhub_vals,
                            const int* __restrict__ ofs_e, const int* __restrict__ ofs_n,
                            int* __restrict__ cur_e, int* __restrict__ cur_n,
                            int* __restrict__ csr_e_node, float* __restrict__ csr_e_v1, float* __restrict__ csr_e_v2,
                            int* __restrict__ csr_n_edge, float* __restrict__ csr_n_v1, float* __restrict__ csr_n_v2) {
    int i = blockIdx.x * 256 + threadIdx.x;
    int e = hedge_idx[i];
    int n = node_idx[i];
    int pe = atomicAdd(&cur_e[e], 1);
    int oe = ofs_e[e] + pe;
    csr_e_node[oe] = n;
    csr_e_v1[oe] = 0.5f * hd_vals[i];
    csr_e_v2[oe] = bhub_vals[i];
    int pn = atomicAdd(&cur_n[n], 1);
    int on = ofs_n[n] + pn;
    csr_n_edge[on] = e;
    csr_n_v1[on] = 0.5f * hb_vals[i];
    csr_n_v2[on] = dhwd_vals[i];
}

// ---------------- W prep: fp32 [4][128][128] -> bf16 hi/lo planes ----------------
__global__ void wprep_kernel(const float* __restrict__ W0, const float* __restrict__ W1,
                             const float* __restrict__ W2, const float* __restrict__ W3,
                             unsigned short* __restrict__ whi, unsigned short* __restrict__ wlo) {
    int mat = blockIdx.x >> 6;
    int off = (blockIdx.x & 63) * 256 + threadIdx.x;
    const float* W = (mat == 0) ? W0 : (mat == 1) ? W1 : (mat == 2) ? W2 : W3;
    float f = W[off];
    unsigned int h = bfrn(f);
    float hf = __uint_as_float(h << 16);
    unsigned int l = bfrn(f - hf);
    int idx = mat * 16384 + off;
    whi[idx] = (unsigned short)h;
    wlo[idx] = (unsigned short)l;
}

// ---------------- MFMA dual GEMM (bf16 3-term split, fp32-accurate) ----------------
// outA = in @ WA^T + bA ; outB = in @ WB^T + bB.  whi/wlo hold [2][128][128] bf16 planes.
// Block: 256 thr = 4 waves; 128 rows/block; wave w: matrix w>>1, cols (w&1)*64..+63.
__global__ __launch_bounds__(256, 2) void gemm_mfma(const float* __restrict__ in,
                                                    const unsigned short* __restrict__ whi,
                                                    const unsigned short* __restrict__ wlo,
                                                    const float* __restrict__ bA,
                                                    const float* __restrict__ bB,
                                                    float* __restrict__ outA,
                                                    float* __restrict__ outB) {
    __shared__ uint4 AH[2][4][64];
    __shared__ uint4 AL[2][4][64];
    int t = threadIdx.x;
    int wv = t >> 6, lane = t & 63;
    int row0 = blockIdx.x * 128;

    int mat = wv >> 1;
    const unsigned short* wh = whi + mat * 16384;
    const unsigned short* wl = wlo + mat * 16384;
    int colbase = (wv & 1) * 64;
    int ln15 = lane & 15;
    int kb = 8 * (lane >> 4);

    bfrag8 bh[4][4], bl[4][4];  // [ct][kstep]
#pragma unroll
    for (int ct = 0; ct < 4; ++ct) {
        int n = colbase + ct * 16 + ln15;
#pragma unroll
        for (int ks = 0; ks < 4; ++ks) {
            bh[ct][ks] = *(const bfrag8*)&wh[n * 128 + ks * 32 + kb];
            bl[ct][ks] = *(const bfrag8*)&wl[n * 128 + ks * 32 + kb];
        }
    }
    const float* bias = mat ? bB : bA;
    float biasv[4];
#pragma unroll
    for (int ct = 0; ct < 4; ++ct) biasv[ct] = bias[colbase + ct * 16 + ln15];
    float* outp = mat ? outB : outA;

    // stage row-tile rt (16 rows x 128 k) into buffer b, fragment-ordered, bf16 hi/lo
    auto STAGE = [&](int rt, int b) {
        int r = row0 + rt * 16 + ln15;
        int k0 = wv * 32 + kb;  // thread's wave index doubles as kstep
        const float* p = &in[(size_t)r * 128 + k0];
        float4 f0 = *(const float4*)p;
        float4 f1 = *(const float4*)(p + 4);
        float fs[8] = {f0.x, f0.y, f0.z, f0.w, f1.x, f1.y, f1.z, f1.w};
        unsigned int hi[4], lo[4];
#pragma unroll
        for (int q = 0; q < 4; ++q) {
            unsigned int h0 = bfrn(fs[2 * q]);
            unsigned int h1 = bfrn(fs[2 * q + 1]);
            float hf0 = __uint_as_float(h0 << 16);
            float hf1 = __uint_as_float(h1 << 16);
            unsigned int l0 = bfrn(fs[2 * q] - hf0);
            unsigned int l1 = bfrn(fs[2 * q + 1] - hf1);
            hi[q] = h0 | (h1 << 16);
            lo[q] = l0 | (l1 << 16);
        }
        AH[b][wv][lane] = make_uint4(hi[0], hi[1], hi[2], hi[3]);
        AL[b][wv][lane] = make_uint4(lo[0], lo[1], lo[2], lo[3]);
    };

    STAGE(0, 0);
    __syncthreads();
    for (int rt = 0; rt < 8; ++rt) {
        int b = rt & 1;
        if (rt < 7) STAGE(rt + 1, b ^ 1);
        f32x4 acc[4];
#pragma unroll
        for (int ct = 0; ct < 4; ++ct) acc[ct] = (f32x4){0.f, 0.f, 0.f, 0.f};
#pragma unroll
        for (int ks = 0; ks < 4; ++ks) {
            bfrag8 ah = *(const bfrag8*)&AH[b][ks][lane];
            bfrag8 al = *(const bfrag8*)&AL[b][ks][lane];
#pragma unroll
            for (int ct = 0; ct < 4; ++ct)
                acc[ct] = __builtin_amdgcn_mfma_f32_16x16x32_bf16(ah, bh[ct][ks], acc[ct], 0, 0, 0);
#pragma unroll
            for (int ct = 0; ct < 4; ++ct)
                acc[ct] = __builtin_amdgcn_mfma_f32_16x16x32_bf16(ah, bl[ct][ks], acc[ct], 0, 0, 0);
#pragma unroll
            for (int ct = 0; ct < 4; ++ct)
                acc[ct] = __builtin_amdgcn_mfma_f32_16x16x32_bf16(al, bh[ct][ks], acc[ct], 0, 0, 0);
        }
        int rbase = row0 + rt * 16 + (lane >> 4) * 4;
#pragma unroll
        for (int ct = 0; ct < 4; ++ct) {
            int c = colbase + ct * 16 + ln15;
#pragma unroll
            for (int rg = 0; rg < 4; ++rg)
                outp[(size_t)(rbase + rg) * 128 + c] = acc[ct][rg] + biasv[ct];
        }
        __syncthreads();
    }
}

// ---------------- gather SpMM: paired-nnz float4 gathers ----------------
// out[row] = init_scale*out[row] + sum_j val[j]*src[tgt[j]]
// Wave = 1 row; half = lane>>5 picks nnz of a pair; 32 lanes x 16B cover the row.
template <int U, bool NT>
__global__ __launch_bounds__(256) void spmm_gather4(const int* __restrict__ ofs,
                                                    const int* __restrict__ tgt,
                                                    const float* __restrict__ val,
                                                    const float* __restrict__ src,
                                                    float* __restrict__ out,
                                                    float init_scale) {
    int row = blockIdx.x * 4 + (threadIdx.x >> 6);
    int lane = threadIdx.x & 63;
    int half = lane >> 5;
    int li = lane & 31;
    int o0 = ofs[row], o1 = ofs[row + 1];
    float4 acc = {0.f, 0.f, 0.f, 0.f};
    int j = o0;
    for (; j + 2 * U - 1 < o1; j += 2 * U) {
        int tg[U];
        float v[U];
#pragma unroll
        for (int u = 0; u < U; ++u) {
            tg[u] = tgt[j + 2 * u + half];
            v[u] = val[j + 2 * u + half];
        }
        float4 m[U];
#pragma unroll
        for (int u = 0; u < U; ++u) m[u] = *(const float4*)&src[(size_t)tg[u] * F + li * 4];
#pragma unroll
        for (int u = 0; u < U; ++u) {
            acc.x += v[u] * m[u].x;
            acc.y += v[u] * m[u].y;
            acc.z += v[u] * m[u].z;
            acc.w += v[u] * m[u].w;
        }
    }
    for (; j < o1; j += 2) {
        int idx = j + half;
        bool ok = idx < o1;
        int tg = ok ? tgt[idx] : tgt[o0];
        float v = ok ? val[idx] : 0.f;
        float4 m = *(const float4*)&src[(size_t)tg * F + li * 4];
        acc.x += v * m.x;
        acc.y += v * m.y;
        acc.z += v * m.z;
        acc.w += v * m.w;
    }
    acc.x += __shfl_down(acc.x, 32);
    acc.y += __shfl_down(acc.y, 32);
    acc.z += __shfl_down(acc.z, 32);
    acc.w += __shfl_down(acc.w, 32);
    if (half == 0) {
        float4* op = (float4*)&out[(size_t)row * F + li * 4];
        if (init_scale != 0.0f) {
            float4 in0 = *op;
            acc.x += init_scale * in0.x;
            acc.y += init_scale * in0.y;
            acc.z += init_scale * in0.z;
            acc.w += init_scale * in0.w;
        }
        if (NT) {
            // __builtin_nontemporal_store needs a true clang vector type,
            // not HIP's float4 struct — go through ext_vector f32x4.
            __builtin_nontemporal_store(*(f32x4*)&acc, (f32x4*)op);
        } else {
            *op = acc;
        }
    }
}

extern "C" void kernel_launch(void* const* d_in, const int* in_sizes, int n_in,
                              void* d_out, int out_size, void* d_ws, size_t ws_size,
                              hipStream_t stream) {
    const float* x = (const float*)d_in[0];
    const float* y = (const float*)d_in[1];
    const int* node_idx = (const int*)d_in[2];
    const int* hedge_idx = (const int*)d_in[3];
    const float* hd_vals = (const float*)d_in[4];
    const float* hb_vals = (const float*)d_in[5];
    const float* dhwd_vals = (const float*)d_in[6];
    const float* bhub_vals = (const float*)d_in[7];
    const float* Qv_w = (const float*)d_in[8];
    const float* Qv_b = (const float*)d_in[9];
    const float* Qe_w = (const float*)d_in[10];
    const float* Qe_b = (const float*)d_in[11];
    const float* Pe_w = (const float*)d_in[12];
    const float* Pe_b = (const float*)d_in[13];
    const float* Pv_w = (const float*)d_in[14];
    const float* Pv_b = (const float*)d_in[15];

    float* X = (float*)d_out;                   // final X [N,F]; scratch: qvx
    float* Y = (float*)d_out + (size_t)NN * F;  // final Y [E,F]; scratch: pey
    float* qvx = X;
    float* pey = Y;

    char* w = (char*)d_ws;
    float* t_n        = (float*)(w + 0);          // [N,F]  (pvx, then t_n)
    float* t_e        = (float*)(w + 33554432);   // [E,F]  (qey, then t_e)
    int*   csr_e_node = (int*)  (w + 41943040);
    float* csr_e_v1   = (float*)(w + 45088768);
    float* csr_e_v2   = (float*)(w + 48234496);
    int*   csr_n_edge = (int*)  (w + 51380224);
    float* csr_n_v1   = (float*)(w + 54525952);
    float* csr_n_v2   = (float*)(w + 57671680);
    int*   cnt_e      = (int*)  (w + 60817408);
    int*   cnt_n      = (int*)  (w + 60882944);   // dead after node scan_p1 -> reused for W planes
    int*   cur_e      = (int*)  (w + 61145088);
    int*   cur_n      = (int*)  (w + 61210624);
    int*   ofs_e      = (int*)  (w + 61472768);
    int*   ofs_n      = (int*)  (w + 61538560);
    int*   bsum       = (int*)  (w + 61800960);
    // W bf16 planes overlap the dead cnt_n region: 4*16384*2B = 128KB each
    unsigned short* whi = (unsigned short*)(w + 60882944);
    unsigned short* wlo = (unsigned short*)(w + 60882944 + 131072);

    // zero cnt_e, cnt_n, cur_e, cur_n
    (void)hipMemsetAsync(cnt_e, 0, (size_t)2 * (EE + NN) * 4, stream);

    hist_kernel<<<NNZT / 1024, 256, 0, stream>>>((const int4*)hedge_idx, (const int4*)node_idx,
                                                 cnt_e, cnt_n);

    scan_p1<<<EE / 1024, 1024, 0, stream>>>(cnt_e, ofs_e, bsum);
    scan_p2<<<1, 64, 0, stream>>>(bsum, EE / 1024, &ofs_e[EE]);
    scan_p3<<<EE / 1024, 1024, 0, stream>>>(ofs_e, bsum);
    scan_p1<<<NN / 1024, 1024, 0, stream>>>(cnt_n, ofs_n, bsum);
    scan_p2<<<1, 64, 0, stream>>>(bsum, NN / 1024, &ofs_n[NN]);
    scan_p3<<<NN / 1024, 1024, 0, stream>>>(ofs_n, bsum);

    fill_kernel<<<NNZT / 256, 256, 0, stream>>>(node_idx, hedge_idx, hd_vals, hb_vals,
                                                dhwd_vals, bhub_vals, ofs_e, ofs_n,
                                                cur_e, cur_n,
                                                csr_e_node, csr_e_v1, csr_e_v2,
                                                csr_n_edge, csr_n_v1, csr_n_v2);

    // W -> bf16 hi/lo planes (cnt_n is dead from here on)
    wprep_kernel<<<256, 256, 0, stream>>>(Qv_w, Pv_w, Qe_w, Pe_w, whi, wlo);

    // GEMMs (MFMA, 3-term split): qvx/pvx from x ; qey/pey from y
    gemm_mfma<<<NN / 128, 256, 0, stream>>>(x, whi, wlo, Qv_b, Pv_b, qvx, t_n);
    gemm_mfma<<<EE / 128, 256, 0, stream>>>(y, whi + 2 * 16384, wlo + 2 * 16384,
                                            Qe_b, Pe_b, t_e, pey);

    // phase A: t_e = 0.5*qey + seg_e(0.5*hd*qvx[node]) ; t_n = 0.5*pvx + seg_n(0.5*hb*pey[hedge])
    spmm_gather4<4, false><<<EE / 4, 256, 0, stream>>>(ofs_e, csr_e_node, csr_e_v1, qvx, t_e, 0.5f);
    spmm_gather4<4, false><<<NN / 4, 256, 0, stream>>>(ofs_n, csr_n_edge, csr_n_v1, pey, t_n, 0.5f);

    // phase B: X = seg_n(dhwd*t_e[hedge]) ; Y = seg_e(bhub*t_n[node])
    spmm_gather4<4, true><<<NN / 4, 256, 0, stream>>>(ofs_n, csr_n_edge, csr_n_v2, t_e, X, 0.0f);
    spmm_gather4<4, true><<<EE / 4, 256, 0, stream>>>(ofs_e, csr_e_node, csr_e_v2, t_n, Y, 0.0f);
}

// Round 8
// 515.616 us; speedup vs baseline: 1.2885x; 1.0782x over previous
//
#include <hip/hip_runtime.h>

#define F 128
#define NN 65536
#define EE 16384
#define NNZT 786432

typedef __attribute__((ext_vector_type(8))) short bfrag8;
typedef __attribute__((ext_vector_type(4))) float f32x4;

// round-to-nearest-even fp32 -> bf16 bits
__device__ __forceinline__ unsigned int bfrn(float f) {
    unsigned int u = __float_as_uint(f);
    return (u + 0x7fffu + ((u >> 16) & 1u)) >> 16;
}

// ---------------- histogram (int4-vectorized: 4 nnz/thread) ----------------
__global__ void hist_kernel(const int4* __restrict__ hedge_idx4,
                            const int4* __restrict__ node_idx4,
                            int* __restrict__ cnt_e, int* __restrict__ cnt_n) {
    int i = blockIdx.x * 256 + threadIdx.x;
    int4 e = hedge_idx4[i];
    int4 n = node_idx4[i];
    atomicAdd(&cnt_e[e.x], 1);
    atomicAdd(&cnt_e[e.y], 1);
    atomicAdd(&cnt_e[e.z], 1);
    atomicAdd(&cnt_e[e.w], 1);
    atomicAdd(&cnt_n[n.x], 1);
    atomicAdd(&cnt_n[n.y], 1);
    atomicAdd(&cnt_n[n.z], 1);
    atomicAdd(&cnt_n[n.w], 1);
}

// ---------------- 3-phase exclusive scan (n multiple of 1024) ----------------
__global__ __launch_bounds__(1024) void scan_p1(const int* __restrict__ cnt,
                                                int* __restrict__ ofs,
                                                int* __restrict__ bsum) {
    __shared__ int wsum[16];
    int t = threadIdx.x, lane = t & 63, w = t >> 6;
    int g = blockIdx.x * 1024 + t;
    int v = cnt[g];
    int inc = v;
#pragma unroll
    for (int d = 1; d < 64; d <<= 1) {
        int u = __shfl_up(inc, d);
        if (lane >= d) inc += u;
    }
    if (lane == 63) wsum[w] = inc;
    __syncthreads();
    if (t < 16) {
        int s = wsum[t];
#pragma unroll
        for (int d = 1; d < 16; d <<= 1) {
            int u = __shfl_up(s, d);
            if (t >= d) s += u;
        }
        wsum[t] = s;
    }
    __syncthreads();
    int woff = (w == 0) ? 0 : wsum[w - 1];
    ofs[g] = woff + inc - v;
    if (t == 1023) bsum[blockIdx.x] = wsum[15];
}

__global__ void scan_p2(int* __restrict__ bsum, int nb, int* __restrict__ ofs_end) {
    int lane = threadIdx.x;
    int v = (lane < nb) ? bsum[lane] : 0;
    int inc = v;
#pragma unroll
    for (int d = 1; d < 64; d <<= 1) {
        int u = __shfl_up(inc, d);
        if (lane >= d) inc += u;
    }
    if (lane < nb) bsum[lane] = inc - v;
    if (lane == 63) *ofs_end = inc;
}

__global__ __launch_bounds__(1024) void scan_p3(int* __restrict__ ofs,
                                                const int* __restrict__ bsum) {
    int g = blockIdx.x * 1024 + threadIdx.x;
    ofs[g] += bsum[blockIdx.x];
}

// ---------------- inverse-permutation fill (only 2 scattered 4B stores/nnz) ----------------
__global__ void invfill_kernel(const int* __restrict__ node_idx, const int* __restrict__ hedge_idx,
                               const int* __restrict__ ofs_e, const int* __restrict__ ofs_n,
                               int* __restrict__ cur_e, int* __restrict__ cur_n,
                               int* __restrict__ inv_e, int* __restrict__ inv_n) {
    int i = blockIdx.x * 256 + threadIdx.x;
    int e = hedge_idx[i];
    int pe = atomicAdd(&cur_e[e], 1);
    inv_e[ofs_e[e] + pe] = i;
    int n = node_idx[i];
    int pn = atomicAdd(&cur_n[n], 1);
    inv_n[ofs_n[n] + pn] = i;
}

// ---------------- W prep: fp32 [4][128][128] -> bf16 hi/lo planes ----------------
__global__ void wprep_kernel(const float* __restrict__ W0, const float* __restrict__ W1,
                             const float* __restrict__ W2, const float* __restrict__ W3,
                             unsigned short* __restrict__ whi, unsigned short* __restrict__ wlo) {
    int mat = blockIdx.x >> 6;
    int off = (blockIdx.x & 63) * 256 + threadIdx.x;
    const float* W = (mat == 0) ? W0 : (mat == 1) ? W1 : (mat == 2) ? W2 : W3;
    float f = W[off];
    unsigned int h = bfrn(f);
    float hf = __uint_as_float(h << 16);
    unsigned int l = bfrn(f - hf);
    int idx = mat * 16384 + off;
    whi[idx] = (unsigned short)h;
    wlo[idx] = (unsigned short)l;
}

// ---------------- MFMA dual GEMM (bf16 3-term split, fp32-accurate) ----------------
// outA = in @ WA^T + bA ; outB = in @ WB^T + bB. Output dtype per-template (bf16 or fp32).
template <bool ABF16, bool BBF16>
__global__ __launch_bounds__(256, 2) void gemm_mfma(const float* __restrict__ in,
                                                    const unsigned short* __restrict__ whi,
                                                    const unsigned short* __restrict__ wlo,
                                                    const float* __restrict__ bA,
                                                    const float* __restrict__ bB,
                                                    void* __restrict__ outA,
                                                    void* __restrict__ outB) {
    __shared__ uint4 AH[2][4][64];
    __shared__ uint4 AL[2][4][64];
    int t = threadIdx.x;
    int wv = t >> 6, lane = t & 63;
    int row0 = blockIdx.x * 128;

    int mat = wv >> 1;
    const unsigned short* wh = whi + mat * 16384;
    const unsigned short* wl = wlo + mat * 16384;
    int colbase = (wv & 1) * 64;
    int ln15 = lane & 15;
    int kb = 8 * (lane >> 4);

    bfrag8 bh[4][4], bl[4][4];  // [ct][kstep]
#pragma unroll
    for (int ct = 0; ct < 4; ++ct) {
        int n = colbase + ct * 16 + ln15;
#pragma unroll
        for (int ks = 0; ks < 4; ++ks) {
            bh[ct][ks] = *(const bfrag8*)&wh[n * 128 + ks * 32 + kb];
            bl[ct][ks] = *(const bfrag8*)&wl[n * 128 + ks * 32 + kb];
        }
    }
    const float* bias = mat ? bB : bA;
    float biasv[4];
#pragma unroll
    for (int ct = 0; ct < 4; ++ct) biasv[ct] = bias[colbase + ct * 16 + ln15];
    void* outp = mat ? outB : outA;
    bool obf = mat ? BBF16 : ABF16;

    auto STAGE = [&](int rt, int b) {
        int r = row0 + rt * 16 + ln15;
        int k0 = wv * 32 + kb;
        const float* p = &in[(size_t)r * 128 + k0];
        float4 f0 = *(const float4*)p;
        float4 f1 = *(const float4*)(p + 4);
        float fs[8] = {f0.x, f0.y, f0.z, f0.w, f1.x, f1.y, f1.z, f1.w};
        unsigned int hi[4], lo[4];
#pragma unroll
        for (int q = 0; q < 4; ++q) {
            unsigned int h0 = bfrn(fs[2 * q]);
            unsigned int h1 = bfrn(fs[2 * q + 1]);
            float hf0 = __uint_as_float(h0 << 16);
            float hf1 = __uint_as_float(h1 << 16);
            unsigned int l0 = bfrn(fs[2 * q] - hf0);
            unsigned int l1 = bfrn(fs[2 * q + 1] - hf1);
            hi[q] = h0 | (h1 << 16);
            lo[q] = l0 | (l1 << 16);
        }
        AH[b][wv][lane] = make_uint4(hi[0], hi[1], hi[2], hi[3]);
        AL[b][wv][lane] = make_uint4(lo[0], lo[1], lo[2], lo[3]);
    };

    STAGE(0, 0);
    __syncthreads();
    for (int rt = 0; rt < 8; ++rt) {
        int b = rt & 1;
        if (rt < 7) STAGE(rt + 1, b ^ 1);
        f32x4 acc[4];
#pragma unroll
        for (int ct = 0; ct < 4; ++ct) acc[ct] = (f32x4){0.f, 0.f, 0.f, 0.f};
#pragma unroll
        for (int ks = 0; ks < 4; ++ks) {
            bfrag8 ah = *(const bfrag8*)&AH[b][ks][lane];
            bfrag8 al = *(const bfrag8*)&AL[b][ks][lane];
#pragma unroll
            for (int ct = 0; ct < 4; ++ct)
                acc[ct] = __builtin_amdgcn_mfma_f32_16x16x32_bf16(ah, bh[ct][ks], acc[ct], 0, 0, 0);
#pragma unroll
            for (int ct = 0; ct < 4; ++ct)
                acc[ct] = __builtin_amdgcn_mfma_f32_16x16x32_bf16(ah, bl[ct][ks], acc[ct], 0, 0, 0);
#pragma unroll
            for (int ct = 0; ct < 4; ++ct)
                acc[ct] = __builtin_amdgcn_mfma_f32_16x16x32_bf16(al, bh[ct][ks], acc[ct], 0, 0, 0);
        }
        int rbase = row0 + rt * 16 + (lane >> 4) * 4;
#pragma unroll
        for (int ct = 0; ct < 4; ++ct) {
            int c = colbase + ct * 16 + ln15;
#pragma unroll
            for (int rg = 0; rg < 4; ++rg) {
                float v = acc[ct][rg] + biasv[ct];
                if (obf)
                    ((unsigned short*)outp)[(size_t)(rbase + rg) * 128 + c] = (unsigned short)bfrn(v);
                else
                    ((float*)outp)[(size_t)(rbase + rg) * 128 + c] = v;
            }
        }
        __syncthreads();
    }
}

// ---------------- gather SpMM over bf16 sources, via inverse permutation ----------------
// out[row] = iscale*initsrc[row] + vscale * sum_{slot in row} val[inv[slot]] * src[idx[inv[slot]]]
// Wave = 1 row; quarter q=lane>>4 handles slot j+q; 16 lanes x 16B (8 bf16) cover the 256B row.
template <int U, bool BF16OUT, bool HASINIT>
__global__ __launch_bounds__(256) void spmm_g(const int* __restrict__ ofs,
                                              const int* __restrict__ inv,
                                              const int* __restrict__ idxarr,
                                              const float* __restrict__ valarr,
                                              float vscale,
                                              const unsigned short* __restrict__ src,
                                              const float* __restrict__ initsrc,
                                              float iscale,
                                              void* __restrict__ outp) {
    int row = blockIdx.x * 4 + (threadIdx.x >> 6);
    int lane = threadIdx.x & 63;
    int q = lane >> 4;
    int li = lane & 15;
    int o0 = ofs[row], o1 = ofs[row + 1];
    float acc[8] = {};
    for (int j = o0; j < o1; j += 4 * U) {
#pragma unroll
        for (int u = 0; u < U; ++u) {
            int slot = j + 4 * u + q;
            bool ok = slot < o1;
            int ss = ok ? slot : o0;
            int iv = inv[ss];
            int tg = idxarr[iv];
            float v = ok ? valarr[iv] * vscale : 0.f;
            uint4 rb = *(const uint4*)&src[(size_t)tg * F + li * 8];
            unsigned int rw0 = rb.x, rw1 = rb.y, rw2 = rb.z, rw3 = rb.w;
            acc[0] += v * __uint_as_float(rw0 << 16);
            acc[1] += v * __uint_as_float(rw0 & 0xffff0000u);
            acc[2] += v * __uint_as_float(rw1 << 16);
            acc[3] += v * __uint_as_float(rw1 & 0xffff0000u);
            acc[4] += v * __uint_as_float(rw2 << 16);
            acc[5] += v * __uint_as_float(rw2 & 0xffff0000u);
            acc[6] += v * __uint_as_float(rw3 << 16);
            acc[7] += v * __uint_as_float(rw3 & 0xffff0000u);
        }
    }
#pragma unroll
    for (int k = 0; k < 8; ++k) {
        acc[k] += __shfl_down(acc[k], 32);
        acc[k] += __shfl_down(acc[k], 16);
    }
    if (q == 0) {
        if (HASINIT) {
            const float4* ip = (const float4*)&initsrc[(size_t)row * F + li * 8];
            float4 i0 = ip[0], i1 = ip[1];
            acc[0] += iscale * i0.x;
            acc[1] += iscale * i0.y;
            acc[2] += iscale * i0.z;
            acc[3] += iscale * i0.w;
            acc[4] += iscale * i1.x;
            acc[5] += iscale * i1.y;
            acc[6] += iscale * i1.z;
            acc[7] += iscale * i1.w;
        }
        if (BF16OUT) {
            unsigned short* ob = (unsigned short*)outp;
            uint4 wv;
            wv.x = bfrn(acc[0]) | (bfrn(acc[1]) << 16);
            wv.y = bfrn(acc[2]) | (bfrn(acc[3]) << 16);
            wv.z = bfrn(acc[4]) | (bfrn(acc[5]) << 16);
            wv.w = bfrn(acc[6]) | (bfrn(acc[7]) << 16);
            *(uint4*)&ob[(size_t)row * F + li * 8] = wv;
        } else {
            float* of = (float*)outp;
            float4 s0 = {acc[0], acc[1], acc[2], acc[3]};
            float4 s1 = {acc[4], acc[5], acc[6], acc[7]};
            *(float4*)&of[(size_t)row * F + li * 8] = s0;
            *(float4*)&of[(size_t)row * F + li * 8 + 4] = s1;
        }
    }
}

extern "C" void kernel_launch(void* const* d_in, const int* in_sizes, int n_in,
                              void* d_out, int out_size, void* d_ws, size_t ws_size,
                              hipStream_t stream) {
    const float* x = (const float*)d_in[0];
    const float* y = (const float*)d_in[1];
    const int* node_idx = (const int*)d_in[2];
    const int* hedge_idx = (const int*)d_in[3];
    const float* hd_vals = (const float*)d_in[4];
    const float* hb_vals = (const float*)d_in[5];
    const float* dhwd_vals = (const float*)d_in[6];
    const float* bhub_vals = (const float*)d_in[7];
    const float* Qv_w = (const float*)d_in[8];
    const float* Qv_b = (const float*)d_in[9];
    const float* Qe_w = (const float*)d_in[10];
    const float* Qe_b = (const float*)d_in[11];
    const float* Pe_w = (const float*)d_in[12];
    const float* Pe_b = (const float*)d_in[13];
    const float* Pv_w = (const float*)d_in[14];
    const float* Pv_b = (const float*)d_in[15];

    float* X = (float*)d_out;                   // final X [N,F]
    float* Y = (float*)d_out + (size_t)NN * F;  // final Y [E,F]
    // fp32 intermediates live in d_out until phase B overwrites it:
    float* pvx = X;                              // [N,F] fp32 (dead before X written)
    float* qey = Y;                              // [E,F] fp32 (dead before Y written)

    char* w = (char*)d_ws;
    unsigned short* qvx_b = (unsigned short*)(w + 0);         // [N,F] bf16
    unsigned short* pey_b = (unsigned short*)(w + 16777216);  // [E,F] bf16
    unsigned short* t_e_b = (unsigned short*)(w + 20971520);  // [E,F] bf16
    unsigned short* t_n_b = (unsigned short*)(w + 25165824);  // [N,F] bf16
    int* inv_e = (int*)(w + 41943040);
    int* inv_n = (int*)(w + 45088768);
    int* cnt_e = (int*)(w + 48234496);
    int* cnt_n = (int*)(w + 48300032);
    int* cur_e = (int*)(w + 48562176);
    int* cur_n = (int*)(w + 48627712);
    int* ofs_e = (int*)(w + 48889856);
    int* ofs_n = (int*)(w + 48956416);
    int* bsum  = (int*)(w + 49219072);
    unsigned short* whi = (unsigned short*)(w + 49219328);
    unsigned short* wlo = (unsigned short*)(w + 49350400);

    // zero cnt_e, cnt_n, cur_e, cur_n (contiguous 655360 B)
    (void)hipMemsetAsync(cnt_e, 0, (size_t)2 * (EE + NN) * 4, stream);

    hist_kernel<<<NNZT / 1024, 256, 0, stream>>>((const int4*)hedge_idx, (const int4*)node_idx,
                                                 cnt_e, cnt_n);

    scan_p1<<<EE / 1024, 1024, 0, stream>>>(cnt_e, ofs_e, bsum);
    scan_p2<<<1, 64, 0, stream>>>(bsum, EE / 1024, &ofs_e[EE]);
    scan_p3<<<EE / 1024, 1024, 0, stream>>>(ofs_e, bsum);
    scan_p1<<<NN / 1024, 1024, 0, stream>>>(cnt_n, ofs_n, bsum);
    scan_p2<<<1, 64, 0, stream>>>(bsum, NN / 1024, &ofs_n[NN]);
    scan_p3<<<NN / 1024, 1024, 0, stream>>>(ofs_n, bsum);

    // inverse permutation (replaces full CSR materialization)
    invfill_kernel<<<NNZT / 256, 256, 0, stream>>>(node_idx, hedge_idx, ofs_e, ofs_n,
                                                   cur_e, cur_n, inv_e, inv_n);

    // W -> bf16 hi/lo planes
    wprep_kernel<<<256, 256, 0, stream>>>(Qv_w, Pv_w, Qe_w, Pe_w, whi, wlo);

    // GEMMs: qvx(bf16) + pvx(fp32, in d_out) from x ; qey(fp32, in d_out) + pey(bf16) from y
    gemm_mfma<true, false><<<NN / 128, 256, 0, stream>>>(x, whi, wlo, Qv_b, Pv_b, qvx_b, pvx);
    gemm_mfma<false, true><<<EE / 128, 256, 0, stream>>>(y, whi + 2 * 16384, wlo + 2 * 16384,
                                                         Qe_b, Pe_b, qey, pey_b);

    // phase A: t_e = 0.5*qey + 0.5*seg_e(hd*qvx[node]) ; t_n = 0.5*pvx + 0.5*seg_n(hb*pey[hedge])
    spmm_g<4, true, true><<<EE / 4, 256, 0, stream>>>(ofs_e, inv_e, node_idx, hd_vals, 0.5f,
                                                      qvx_b, qey, 0.5f, t_e_b);
    spmm_g<2, true, true><<<NN / 4, 256, 0, stream>>>(ofs_n, inv_n, hedge_idx, hb_vals, 0.5f,
                                                      pey_b, pvx, 0.5f, t_n_b);

    // phase B: X = seg_n(dhwd*t_e[hedge]) ; Y = seg_e(bhub*t_n[node])
    spmm_g<2, false, false><<<NN / 4, 256, 0, stream>>>(ofs_n, inv_n, hedge_idx, dhwd_vals, 1.0f,
                                                        t_e_b, nullptr, 0.f, X);
    spmm_g<4, false, false><<<EE / 4, 256, 0, stream>>>(ofs_e, inv_e, node_idx, bhub_vals, 1.0f,
                                                        t_n_b, nullptr, 0.f, Y);
}

// Round 10
// 499.119 us; speedup vs baseline: 1.3311x; 1.0331x over previous
//
#include <hip/hip_runtime.h>

#define F 128
#define NN 65536
#define EE 16384
#define NNZT 786432

typedef __attribute__((ext_vector_type(8))) short bfrag8;
typedef __attribute__((ext_vector_type(4))) float f32x4;

// round-to-nearest-even fp32 -> bf16 bits
__device__ __forceinline__ unsigned int bfrn(float f) {
    unsigned int u = __float_as_uint(f);
    return (u + 0x7fffu + ((u >> 16) & 1u)) >> 16;
}

// ---------------- histogram (int4-vectorized: 4 nnz/thread) ----------------
__global__ void hist_kernel(const int4* __restrict__ hedge_idx4,
                            const int4* __restrict__ node_idx4,
                            int* __restrict__ cnt_e, int* __restrict__ cnt_n) {
    int i = blockIdx.x * 256 + threadIdx.x;
    int4 e = hedge_idx4[i];
    int4 n = node_idx4[i];
    atomicAdd(&cnt_e[e.x], 1);
    atomicAdd(&cnt_e[e.y], 1);
    atomicAdd(&cnt_e[e.z], 1);
    atomicAdd(&cnt_e[e.w], 1);
    atomicAdd(&cnt_n[n.x], 1);
    atomicAdd(&cnt_n[n.y], 1);
    atomicAdd(&cnt_n[n.z], 1);
    atomicAdd(&cnt_n[n.w], 1);
}

// ---------------- 3-phase exclusive scan (n multiple of 1024) ----------------
__global__ __launch_bounds__(1024) void scan_p1(const int* __restrict__ cnt,
                                                int* __restrict__ ofs,
                                                int* __restrict__ bsum) {
    __shared__ int wsum[16];
    int t = threadIdx.x, lane = t & 63, w = t >> 6;
    int g = blockIdx.x * 1024 + t;
    int v = cnt[g];
    int inc = v;
#pragma unroll
    for (int d = 1; d < 64; d <<= 1) {
        int u = __shfl_up(inc, d);
        if (lane >= d) inc += u;
    }
    if (lane == 63) wsum[w] = inc;
    __syncthreads();
    if (t < 16) {
        int s = wsum[t];
#pragma unroll
        for (int d = 1; d < 16; d <<= 1) {
            int u = __shfl_up(s, d);
            if (t >= d) s += u;
        }
        wsum[t] = s;
    }
    __syncthreads();
    int woff = (w == 0) ? 0 : wsum[w - 1];
    ofs[g] = woff + inc - v;
    if (t == 1023) bsum[blockIdx.x] = wsum[15];
}

__global__ void scan_p2(int* __restrict__ bsum, int nb, int* __restrict__ ofs_end) {
    int lane = threadIdx.x;
    int v = (lane < nb) ? bsum[lane] : 0;
    int inc = v;
#pragma unroll
    for (int d = 1; d < 64; d <<= 1) {
        int u = __shfl_up(inc, d);
        if (lane >= d) inc += u;
    }
    if (lane < nb) bsum[lane] = inc - v;
    if (lane == 63) *ofs_end = inc;
}

__global__ __launch_bounds__(1024) void scan_p3(int* __restrict__ ofs,
                                                const int* __restrict__ bsum) {
    int g = blockIdx.x * 1024 + threadIdx.x;
    ofs[g] += bsum[blockIdx.x];
}

// ---------------- XCD-sliced inverse-permutation fill ----------------
// slice = blockIdx&7 -> one of 8 target-ID buckets (maps ~1:1 onto XCDs).
// Each slice streams the full index arrays but scatters only into its own
// bucket: per-XCD write working set ~800KB -> L2-resident, no line churn.
__global__ __launch_bounds__(256) void invfill_sliced(const int4* __restrict__ hedge4,
                                                      const int4* __restrict__ node4,
                                                      const int* __restrict__ ofs_e,
                                                      const int* __restrict__ ofs_n,
                                                      int* __restrict__ cur_e,
                                                      int* __restrict__ cur_n,
                                                      int* __restrict__ inv_e,
                                                      int* __restrict__ inv_n) {
    int slice = blockIdx.x & 7;
    int bs = blockIdx.x >> 3;  // 0..95
    int elo = slice << 11, ehi = elo + (EE >> 3);
    int nlo = slice << 13, nhi = nlo + (NN >> 3);
    for (int i4 = bs * 256 + threadIdx.x; i4 < NNZT / 4; i4 += 96 * 256) {
        int4 e4 = hedge4[i4];
        int4 n4 = node4[i4];
        int base = i4 * 4;
        int es[4] = {e4.x, e4.y, e4.z, e4.w};
        int ns[4] = {n4.x, n4.y, n4.z, n4.w};
#pragma unroll
        for (int u = 0; u < 4; ++u) {
            int e = es[u];
            if (e >= elo && e < ehi) {
                int p = atomicAdd(&cur_e[e], 1);
                inv_e[ofs_e[e] + p] = base + u;
            }
            int n = ns[u];
            if (n >= nlo && n < nhi) {
                int p = atomicAdd(&cur_n[n], 1);
                inv_n[ofs_n[n] + p] = base + u;
            }
        }
    }
}

// ---------------- W prep: fp32 [4][128][128] -> bf16 hi/lo planes ----------------
__global__ void wprep_kernel(const float* __restrict__ W0, const float* __restrict__ W1,
                             const float* __restrict__ W2, const float* __restrict__ W3,
                             unsigned short* __restrict__ whi, unsigned short* __restrict__ wlo) {
    int mat = blockIdx.x >> 6;
    int off = (blockIdx.x & 63) * 256 + threadIdx.x;
    const float* W = (mat == 0) ? W0 : (mat == 1) ? W1 : (mat == 2) ? W2 : W3;
    float f = W[off];
    unsigned int h = bfrn(f);
    float hf = __uint_as_float(h << 16);
    unsigned int l = bfrn(f - hf);
    int idx = mat * 16384 + off;
    whi[idx] = (unsigned short)h;
    wlo[idx] = (unsigned short)l;
}

// ---------------- MFMA dual GEMM (bf16 3-term split, fp32-accurate) ----------------
// outA = in @ WA^T + bA ; outB = in @ WB^T + bB. Output dtype per-template (bf16 or fp32).
template <bool ABF16, bool BBF16>
__global__ __launch_bounds__(256, 2) void gemm_mfma(const float* __restrict__ in,
                                                    const unsigned short* __restrict__ whi,
                                                    const unsigned short* __restrict__ wlo,
                                                    const float* __restrict__ bA,
                                                    const float* __restrict__ bB,
                                                    void* __restrict__ outA,
                                                    void* __restrict__ outB) {
    __shared__ uint4 AH[2][4][64];
    __shared__ uint4 AL[2][4][64];
    int t = threadIdx.x;
    int wv = t >> 6, lane = t & 63;
    int row0 = blockIdx.x * 128;

    int mat = wv >> 1;
    const unsigned short* wh = whi + mat * 16384;
    const unsigned short* wl = wlo + mat * 16384;
    int colbase = (wv & 1) * 64;
    int ln15 = lane & 15;
    int kb = 8 * (lane >> 4);

    bfrag8 bh[4][4], bl[4][4];  // [ct][kstep]
#pragma unroll
    for (int ct = 0; ct < 4; ++ct) {
        int n = colbase + ct * 16 + ln15;
#pragma unroll
        for (int ks = 0; ks < 4; ++ks) {
            bh[ct][ks] = *(const bfrag8*)&wh[n * 128 + ks * 32 + kb];
            bl[ct][ks] = *(const bfrag8*)&wl[n * 128 + ks * 32 + kb];
        }
    }
    const float* bias = mat ? bB : bA;
    float biasv[4];
#pragma unroll
    for (int ct = 0; ct < 4; ++ct) biasv[ct] = bias[colbase + ct * 16 + ln15];
    void* outp = mat ? outB : outA;
    bool obf = mat ? BBF16 : ABF16;

    auto STAGE = [&](int rt, int b) {
        int r = row0 + rt * 16 + ln15;
        int k0 = wv * 32 + kb;
        const float* p = &in[(size_t)r * 128 + k0];
        float4 f0 = *(const float4*)p;
        float4 f1 = *(const float4*)(p + 4);
        float fs[8] = {f0.x, f0.y, f0.z, f0.w, f1.x, f1.y, f1.z, f1.w};
        unsigned int hi[4], lo[4];
#pragma unroll
        for (int q = 0; q < 4; ++q) {
            unsigned int h0 = bfrn(fs[2 * q]);
            unsigned int h1 = bfrn(fs[2 * q + 1]);
            float hf0 = __uint_as_float(h0 << 16);
            float hf1 = __uint_as_float(h1 << 16);
            unsigned int l0 = bfrn(fs[2 * q] - hf0);
            unsigned int l1 = bfrn(fs[2 * q + 1] - hf1);
            hi[q] = h0 | (h1 << 16);
            lo[q] = l0 | (l1 << 16);
        }
        AH[b][wv][lane] = make_uint4(hi[0], hi[1], hi[2], hi[3]);
        AL[b][wv][lane] = make_uint4(lo[0], lo[1], lo[2], lo[3]);
    };

    STAGE(0, 0);
    __syncthreads();
    for (int rt = 0; rt < 8; ++rt) {
        int b = rt & 1;
        if (rt < 7) STAGE(rt + 1, b ^ 1);
        f32x4 acc[4];
#pragma unroll
        for (int ct = 0; ct < 4; ++ct) acc[ct] = (f32x4){0.f, 0.f, 0.f, 0.f};
#pragma unroll
        for (int ks = 0; ks < 4; ++ks) {
            bfrag8 ah = *(const bfrag8*)&AH[b][ks][lane];
            bfrag8 al = *(const bfrag8*)&AL[b][ks][lane];
#pragma unroll
            for (int ct = 0; ct < 4; ++ct)
                acc[ct] = __builtin_amdgcn_mfma_f32_16x16x32_bf16(ah, bh[ct][ks], acc[ct], 0, 0, 0);
#pragma unroll
            for (int ct = 0; ct < 4; ++ct)
                acc[ct] = __builtin_amdgcn_mfma_f32_16x16x32_bf16(ah, bl[ct][ks], acc[ct], 0, 0, 0);
#pragma unroll
            for (int ct = 0; ct < 4; ++ct)
                acc[ct] = __builtin_amdgcn_mfma_f32_16x16x32_bf16(al, bh[ct][ks], acc[ct], 0, 0, 0);
        }
        int rbase = row0 + rt * 16 + (lane >> 4) * 4;
#pragma unroll
        for (int ct = 0; ct < 4; ++ct) {
            int c = colbase + ct * 16 + ln15;
#pragma unroll
            for (int rg = 0; rg < 4; ++rg) {
                float v = acc[ct][rg] + biasv[ct];
                if (obf)
                    ((unsigned short*)outp)[(size_t)(rbase + rg) * 128 + c] = (unsigned short)bfrn(v);
                else
                    ((float*)outp)[(size_t)(rbase + rg) * 128 + c] = v;
            }
        }
        __syncthreads();
    }
}

// ---------------- gather SpMM over bf16 sources, via inverse permutation ----------------
// out[row] = iscale*initsrc[row] + vscale * sum_{slot in row} val[inv[slot]] * src[idx[inv[slot]]]
// Wave = 1 row; quarter q=lane>>4 handles slot j+q; 16 lanes x 16B (8 bf16) cover the 256B row.
template <int U, bool BF16OUT, bool HASINIT>
__global__ __launch_bounds__(256) void spmm_g(const int* __restrict__ ofs,
                                              const int* __restrict__ inv,
                                              const int* __restrict__ idxarr,
                                              const float* __restrict__ valarr,
                                              float vscale,
                                              const unsigned short* __restrict__ src,
                                              const float* __restrict__ initsrc,
                                              float iscale,
                                              void* __restrict__ outp) {
    int row = blockIdx.x * 4 + (threadIdx.x >> 6);
    int lane = threadIdx.x & 63;
    int q = lane >> 4;
    int li = lane & 15;
    int o0 = ofs[row], o1 = ofs[row + 1];
    float acc[8] = {};
    for (int j = o0; j < o1; j += 4 * U) {
#pragma unroll
        for (int u = 0; u < U; ++u) {
            int slot = j + 4 * u + q;
            bool ok = slot < o1;
            int ss = ok ? slot : o0;
            int iv = inv[ss];
            int tg = idxarr[iv];
            float v = ok ? valarr[iv] * vscale : 0.f;
            uint4 rb = *(const uint4*)&src[(size_t)tg * F + li * 8];
            unsigned int rw0 = rb.x, rw1 = rb.y, rw2 = rb.z, rw3 = rb.w;
            acc[0] += v * __uint_as_float(rw0 << 16);
            acc[1] += v * __uint_as_float(rw0 & 0xffff0000u);
            acc[2] += v * __uint_as_float(rw1 << 16);
            acc[3] += v * __uint_as_float(rw1 & 0xffff0000u);
            acc[4] += v * __uint_as_float(rw2 << 16);
            acc[5] += v * __uint_as_float(rw2 & 0xffff0000u);
            acc[6] += v * __uint_as_float(rw3 << 16);
            acc[7] += v * __uint_as_float(rw3 & 0xffff0000u);
        }
    }
#pragma unroll
    for (int k = 0; k < 8; ++k) {
        acc[k] += __shfl_down(acc[k], 32);
        acc[k] += __shfl_down(acc[k], 16);
    }
    if (q == 0) {
        if (HASINIT) {
            const float4* ip = (const float4*)&initsrc[(size_t)row * F + li * 8];
            float4 i0 = ip[0], i1 = ip[1];
            acc[0] += iscale * i0.x;
            acc[1] += iscale * i0.y;
            acc[2] += iscale * i0.z;
            acc[3] += iscale * i0.w;
            acc[4] += iscale * i1.x;
            acc[5] += iscale * i1.y;
            acc[6] += iscale * i1.z;
            acc[7] += iscale * i1.w;
        }
        if (BF16OUT) {
            unsigned short* ob = (unsigned short*)outp;
            uint4 wv;
            wv.x = bfrn(acc[0]) | (bfrn(acc[1]) << 16);
            wv.y = bfrn(acc[2]) | (bfrn(acc[3]) << 16);
            wv.z = bfrn(acc[4]) | (bfrn(acc[5]) << 16);
            wv.w = bfrn(acc[6]) | (bfrn(acc[7]) << 16);
            *(uint4*)&ob[(size_t)row * F + li * 8] = wv;
        } else {
            float* of = (float*)outp;
            float4 s0 = {acc[0], acc[1], acc[2], acc[3]};
            float4 s1 = {acc[4], acc[5], acc[6], acc[7]};
            *(float4*)&of[(size_t)row * F + li * 8] = s0;
            *(float4*)&of[(size_t)row * F + li * 8 + 4] = s1;
        }
    }
}

extern "C" void kernel_launch(void* const* d_in, const int* in_sizes, int n_in,
                              void* d_out, int out_size, void* d_ws, size_t ws_size,
                              hipStream_t stream) {
    const float* x = (const float*)d_in[0];
    const float* y = (const float*)d_in[1];
    const int* node_idx = (const int*)d_in[2];
    const int* hedge_idx = (const int*)d_in[3];
    const float* hd_vals = (const float*)d_in[4];
    const float* hb_vals = (const float*)d_in[5];
    const float* dhwd_vals = (const float*)d_in[6];
    const float* bhub_vals = (const float*)d_in[7];
    const float* Qv_w = (const float*)d_in[8];
    const float* Qv_b = (const float*)d_in[9];
    const float* Qe_w = (const float*)d_in[10];
    const float* Qe_b = (const float*)d_in[11];
    const float* Pe_w = (const float*)d_in[12];
    const float* Pe_b = (const float*)d_in[13];
    const float* Pv_w = (const float*)d_in[14];
    const float* Pv_b = (const float*)d_in[15];

    float* X = (float*)d_out;                   // final X [N,F]
    float* Y = (float*)d_out + (size_t)NN * F;  // final Y [E,F]
    // fp32 intermediates live in d_out until phase B overwrites it:
    float* pvx = X;                              // [N,F] fp32 (dead before X written)
    float* qey = Y;                              // [E,F] fp32 (dead before Y written)

    char* w = (char*)d_ws;
    unsigned short* qvx_b = (unsigned short*)(w + 0);         // [N,F] bf16
    unsigned short* pey_b = (unsigned short*)(w + 16777216);  // [E,F] bf16
    unsigned short* t_e_b = (unsigned short*)(w + 20971520);  // [E,F] bf16
    unsigned short* t_n_b = (unsigned short*)(w + 25165824);  // [N,F] bf16
    int* inv_e = (int*)(w + 41943040);
    int* inv_n = (int*)(w + 45088768);
    int* cnt_e = (int*)(w + 48234496);
    int* cnt_n = (int*)(w + 48300032);
    int* cur_e = (int*)(w + 48562176);
    int* cur_n = (int*)(w + 48627712);
    int* ofs_e = (int*)(w + 48889856);
    int* ofs_n = (int*)(w + 48956416);
    int* bsum  = (int*)(w + 49219072);
    unsigned short* whi = (unsigned short*)(w + 49219328);
    unsigned short* wlo = (unsigned short*)(w + 49350400);

    // zero cnt_e, cnt_n, cur_e, cur_n (contiguous 655360 B)
    (void)hipMemsetAsync(cnt_e, 0, (size_t)2 * (EE + NN) * 4, stream);

    hist_kernel<<<NNZT / 1024, 256, 0, stream>>>((const int4*)hedge_idx, (const int4*)node_idx,
                                                 cnt_e, cnt_n);

    scan_p1<<<EE / 1024, 1024, 0, stream>>>(cnt_e, ofs_e, bsum);
    scan_p2<<<1, 64, 0, stream>>>(bsum, EE / 1024, &ofs_e[EE]);
    scan_p3<<<EE / 1024, 1024, 0, stream>>>(ofs_e, bsum);
    scan_p1<<<NN / 1024, 1024, 0, stream>>>(cnt_n, ofs_n, bsum);
    scan_p2<<<1, 64, 0, stream>>>(bsum, NN / 1024, &ofs_n[NN]);
    scan_p3<<<NN / 1024, 1024, 0, stream>>>(ofs_n, bsum);

    // XCD-sliced inverse permutation (writes L2-localized per slice)
    invfill_sliced<<<768, 256, 0, stream>>>((const int4*)hedge_idx, (const int4*)node_idx,
                                            ofs_e, ofs_n, cur_e, cur_n, inv_e, inv_n);

    // W -> bf16 hi/lo planes
    wprep_kernel<<<256, 256, 0, stream>>>(Qv_w, Pv_w, Qe_w, Pe_w, whi, wlo);

    // GEMMs: qvx(bf16) + pvx(fp32, in d_out) from x ; qey(fp32, in d_out) + pey(bf16) from y
    gemm_mfma<true, false><<<NN / 128, 256, 0, stream>>>(x, whi, wlo, Qv_b, Pv_b, qvx_b, pvx);
    gemm_mfma<false, true><<<EE / 128, 256, 0, stream>>>(y, whi + 2 * 16384, wlo + 2 * 16384,
                                                         Qe_b, Pe_b, qey, pey_b);

    // phase A: t_e = 0.5*qey + 0.5*seg_e(hd*qvx[node]) ; t_n = 0.5*pvx + 0.5*seg_n(hb*pey[hedge])
    spmm_g<4, true, true><<<EE / 4, 256, 0, stream>>>(ofs_e, inv_e, node_idx, hd_vals, 0.5f,
                                                      qvx_b, qey, 0.5f, t_e_b);
    spmm_g<2, true, true><<<NN / 4, 256, 0, stream>>>(ofs_n, inv_n, hedge_idx, hb_vals, 0.5f,
                                                      pey_b, pvx, 0.5f, t_n_b);

    // phase B: X = seg_n(dhwd*t_e[hedge]) ; Y = seg_e(bhub*t_n[node])
    spmm_g<2, false, false><<<NN / 4, 256, 0, stream>>>(ofs_n, inv_n, hedge_idx, dhwd_vals, 1.0f,
                                                        t_e_b, nullptr, 0.f, X);
    spmm_g<4, false, false><<<EE / 4, 256, 0, stream>>>(ofs_e, inv_e, node_idx, bhub_vals, 1.0f,
                                                        t_n_b, nullptr, 0.f, Y);
}